// Round 8
// baseline (526.059 us; speedup 1.0000x reference)
//
#include <hip/hip_runtime.h>

// GCN 4 layers: N=100000, E=1600000, dims 256->128->64->16->40.
//  k_comb : blocks 3:2 split -> {proj1 P1=x@W1 (bf16, un-normalized)} || {degree histogram}
//  CSR    : scan (k_blockscan dual-stores rowptr AND cursor; NO memcpy node) -> fill
//  Gathers: ONE WAVE PER NODE (wave-uniform degree loop, shfl_xor reduce)
//  L1 agg : bf16 gather w/ per-edge nS[s], fused nD+b1+ReLU
//  L2     : proj (global_load_lds staged, bf16 out w/ nS applied) -> bf16 gather
//  L3     : small proj -> wave gather (fused relu+nD+b3, then *nS for L4)
//  L4     : aggregate-first: wave gather t4, fused GEMM (agg@W4)*nD+b4 -> out

typedef unsigned short ushort_t;

__device__ __forceinline__ void gload_lds16(const float4* g, float4* l) {
    __builtin_amdgcn_global_load_lds(
        (const __attribute__((address_space(1))) void*)g,
        (__attribute__((address_space(3))) void*)l, 16, 0, 0);
}

__device__ __forceinline__ ushort_t f2bf(float f) {
    unsigned u = __float_as_uint(f);
    u += 0x7FFFu + ((u >> 16) & 1u);          // RNE
    return (ushort_t)(u >> 16);
}
#define BFLO(u) __uint_as_float((u) << 16)
#define BFHI(u) __uint_as_float((u) & 0xffff0000u)

// ---------------- shared proj GEMM body (global_load_lds staged x and W) ------
template<int DIN, int DOUT, int RB, int KT, typename EPI>
__device__ __forceinline__ void proj_body(
        const float* __restrict__ in, const float* __restrict__ W,
        int N, int n0, float4* __restrict__ wlds, float4* __restrict__ xlds,
        EPI&& epi) {
    constexpr int CG  = DOUT / 4;
    constexpr int RPP = 256 / CG;
    constexpr int R4  = RB / RPP;
    constexpr int K4T = KT / 4;
    constexpr int NKT = DIN / KT;
    constexpr int XTILE = RB * K4T;
    constexpr int WTILE = KT * CG;
    static_assert(RPP * CG == 256, "full block");
    static_assert((K4T & (K4T - 1)) == 0, "pow2 swizzle");
    static_assert(XTILE % 256 == 0 && WTILE % 256 == 0, "stage granularity");

    const int tid  = threadIdx.x;
    const int wave = tid >> 6;
    const int lane = tid & 63;
    const int rp   = tid / CG;
    const int cg   = tid - rp * CG;

    float4 acc[R4];
#pragma unroll
    for (int r = 0; r < R4; ++r) acc[r] = make_float4(0.f, 0.f, 0.f, 0.f);

    for (int kt = 0; kt < NKT; ++kt) {
        const float4* wsrc = (const float4*)(W + (size_t)kt * KT * DOUT);
#pragma unroll
        for (int j = 0; j < WTILE / 256; ++j) {
            int base = j * 256 + wave * 64;
            gload_lds16(wsrc + base + lane, &wlds[base]);
        }
#pragma unroll
        for (int j = 0; j < XTILE / 256; ++j) {
            int base = j * 256 + wave * 64;
            int fi   = base + lane;
            int row  = fi / K4T;
            int k4   = fi - row * K4T;
            int k4s  = k4 ^ (row & (K4T - 1));
            int grow = n0 + row; if (grow >= N) grow = N - 1;
            const float4* gsrc = (const float4*)(in + (size_t)grow * DIN) + kt * K4T + k4s;
            gload_lds16(gsrc, &xlds[base]);
        }
        __syncthreads();
#pragma unroll 2
        for (int k4 = 0; k4 < K4T; ++k4) {
            float4 w0 = wlds[(k4 * 4 + 0) * CG + cg];
            float4 w1 = wlds[(k4 * 4 + 1) * CG + cg];
            float4 w2 = wlds[(k4 * 4 + 2) * CG + cg];
            float4 w3 = wlds[(k4 * 4 + 3) * CG + cg];
#pragma unroll
            for (int r = 0; r < R4; ++r) {
                int row = rp + r * RPP;
                float4 xv = xlds[row * K4T + (k4 ^ (row & (K4T - 1)))];
                acc[r].x = fmaf(xv.x, w0.x, acc[r].x);
                acc[r].y = fmaf(xv.x, w0.y, acc[r].y);
                acc[r].z = fmaf(xv.x, w0.z, acc[r].z);
                acc[r].w = fmaf(xv.x, w0.w, acc[r].w);
                acc[r].x = fmaf(xv.y, w1.x, acc[r].x);
                acc[r].y = fmaf(xv.y, w1.y, acc[r].y);
                acc[r].z = fmaf(xv.y, w1.z, acc[r].z);
                acc[r].w = fmaf(xv.y, w1.w, acc[r].w);
                acc[r].x = fmaf(xv.z, w2.x, acc[r].x);
                acc[r].y = fmaf(xv.z, w2.y, acc[r].y);
                acc[r].z = fmaf(xv.z, w2.z, acc[r].z);
                acc[r].w = fmaf(xv.z, w2.w, acc[r].w);
                acc[r].x = fmaf(xv.w, w3.x, acc[r].x);
                acc[r].y = fmaf(xv.w, w3.y, acc[r].y);
                acc[r].z = fmaf(xv.w, w3.z, acc[r].z);
                acc[r].w = fmaf(xv.w, w3.w, acc[r].w);
            }
        }
        __syncthreads();
    }
    epi(acc, rp, cg);
}

// ---------------- combined: proj1 (bf16, un-normalized) || histogram ----------
template<int DIN, int DOUT, int RB, int KT>
__global__ void __launch_bounds__(256) k_comb(
        const float* __restrict__ x, const float* __restrict__ W,
        ushort_t* __restrict__ outbf, int N,
        const int* __restrict__ src, const int* __restrict__ dst,
        int* __restrict__ degO, int* __restrict__ degI, int E, int PB, int HTH) {
    constexpr int CG  = DOUT / 4;
    constexpr int RPP = 256 / CG;
    constexpr int R4  = RB / RPP;
    constexpr int K4T = KT / 4;
    __shared__ float4 wlds[KT * CG];
    __shared__ float4 xlds[RB * K4T];

    int bid = blockIdx.x, g = bid / 5, r = bid - g * 5;
    if (r >= 3) {
        int i = (g * 2 + (r - 3)) * 256 + (int)threadIdx.x;
        for (; i < E; i += HTH) {
            atomicAdd(&degO[src[i]], 1);
            atomicAdd(&degI[dst[i]], 1);
        }
        return;
    }
    int pidx = g * 3 + r;
    if (pidx >= PB) return;
    int n0 = pidx * RB;
    proj_body<DIN, DOUT, RB, KT>(x, W, N, n0, wlds, xlds,
        [&](float4 (&acc)[R4], int rp, int cg) {
#pragma unroll
            for (int rr = 0; rr < R4; ++rr) {
                int n = n0 + rp + rr * RPP;
                if (n < N) {
                    ushort4 s;
                    s.x = f2bf(acc[rr].x); s.y = f2bf(acc[rr].y);
                    s.z = f2bf(acc[rr].z); s.w = f2bf(acc[rr].w);
                    *(ushort4*)(outbf + (size_t)n * DOUT + cg * 4) = s;
                }
            }
        });
}

// ---------------- proj, bf16 out with *nrm[n] applied -------------------------
template<int DIN, int DOUT, int RB, int KT>
__global__ void __launch_bounds__(256) k_proj_gl2b(
        const float* __restrict__ in, const float* __restrict__ nrm,
        const float* __restrict__ W, ushort_t* __restrict__ outbf, int N) {
    constexpr int CG  = DOUT / 4;
    constexpr int RPP = 256 / CG;
    constexpr int R4  = RB / RPP;
    constexpr int K4T = KT / 4;
    __shared__ float4 wlds[KT * CG];
    __shared__ float4 xlds[RB * K4T];
    int n0 = blockIdx.x * RB;
    proj_body<DIN, DOUT, RB, KT>(in, W, N, n0, wlds, xlds,
        [&](float4 (&acc)[R4], int rp, int cg) {
#pragma unroll
            for (int rr = 0; rr < R4; ++rr) {
                int n = n0 + rp + rr * RPP;
                if (n < N) {
                    float nm = nrm[n];
                    ushort4 s;
                    s.x = f2bf(acc[rr].x * nm); s.y = f2bf(acc[rr].y * nm);
                    s.z = f2bf(acc[rr].z * nm); s.w = f2bf(acc[rr].w * nm);
                    *(ushort4*)(outbf + (size_t)n * DOUT + cg * 4) = s;
                }
            }
        });
}

// ---------------- small proj (global-x), EPI 0: *nrm; 1: *nrm+bias -----------
template<int DIN, int DOUT, int R4, int KT, int EPI>
__global__ void __launch_bounds__(256) k_proj_lds(
        const float* __restrict__ in, const float* __restrict__ nrm,
        const float* __restrict__ W, const float* __restrict__ bias,
        float* __restrict__ out, int N) {
    constexpr int CG  = DOUT / 4;
    constexpr int RPP = 256 / CG;
    constexpr int RB  = RPP * R4;
    constexpr int NKT = DIN / KT;
    __shared__ float4 wlds[KT * CG];

    int tid = threadIdx.x;
    int rp  = tid / CG;
    int cg  = tid - rp * CG;
    bool active = (rp < RPP);
    int n0 = blockIdx.x * RB;

    int nrow[R4];
    const float4* xr[R4];
#pragma unroll
    for (int r = 0; r < R4; ++r) {
        int n = n0 + rp + r * RPP;
        nrow[r] = n;
        int nc = n < N ? n : N - 1;
        xr[r] = (const float4*)(in + (size_t)nc * DIN);
    }
    float4 acc[R4];
#pragma unroll
    for (int r = 0; r < R4; ++r) acc[r] = make_float4(0.f, 0.f, 0.f, 0.f);

    for (int kt = 0; kt < NKT; ++kt) {
        const float4* wsrc = (const float4*)(W + (size_t)kt * KT * DOUT);
        for (int i = tid; i < KT * CG; i += 256) wlds[i] = wsrc[i];
        __syncthreads();
        if (active) {
#pragma unroll 2
            for (int k4 = 0; k4 < KT / 4; ++k4) {
                float4 w0 = wlds[(k4 * 4 + 0) * CG + cg];
                float4 w1 = wlds[(k4 * 4 + 1) * CG + cg];
                float4 w2 = wlds[(k4 * 4 + 2) * CG + cg];
                float4 w3 = wlds[(k4 * 4 + 3) * CG + cg];
#pragma unroll
                for (int r = 0; r < R4; ++r) {
                    float4 xv = xr[r][kt * (KT / 4) + k4];
                    acc[r].x = fmaf(xv.x, w0.x, acc[r].x);
                    acc[r].y = fmaf(xv.x, w0.y, acc[r].y);
                    acc[r].z = fmaf(xv.x, w0.z, acc[r].z);
                    acc[r].w = fmaf(xv.x, w0.w, acc[r].w);
                    acc[r].x = fmaf(xv.y, w1.x, acc[r].x);
                    acc[r].y = fmaf(xv.y, w1.y, acc[r].y);
                    acc[r].z = fmaf(xv.y, w1.z, acc[r].z);
                    acc[r].w = fmaf(xv.y, w1.w, acc[r].w);
                    acc[r].x = fmaf(xv.z, w2.x, acc[r].x);
                    acc[r].y = fmaf(xv.z, w2.y, acc[r].y);
                    acc[r].z = fmaf(xv.z, w2.z, acc[r].z);
                    acc[r].w = fmaf(xv.z, w2.w, acc[r].w);
                    acc[r].x = fmaf(xv.w, w3.x, acc[r].x);
                    acc[r].y = fmaf(xv.w, w3.y, acc[r].y);
                    acc[r].z = fmaf(xv.w, w3.z, acc[r].z);
                    acc[r].w = fmaf(xv.w, w3.w, acc[r].w);
                }
            }
        }
        __syncthreads();
    }
    if (active) {
#pragma unroll
        for (int r = 0; r < R4; ++r) {
            int n = nrow[r];
            if (n < N) {
                float nm = nrm[n];
                float4 o;
                if (EPI == 0) {
                    o = make_float4(acc[r].x * nm, acc[r].y * nm,
                                    acc[r].z * nm, acc[r].w * nm);
                } else {
                    float4 b = *(const float4*)(bias + cg * 4);
                    o.x = fmaf(acc[r].x, nm, b.x);
                    o.y = fmaf(acc[r].y, nm, b.y);
                    o.z = fmaf(acc[r].z, nm, b.z);
                    o.w = fmaf(acc[r].w, nm, b.w);
                }
                *(float4*)(out + (size_t)n * DOUT + cg * 4) = o;
            }
        }
    }
}

// ---------------- norms ----------------
__global__ void k_prep(const int* __restrict__ degO, const int* __restrict__ degI,
                       float* __restrict__ nSf, float* __restrict__ nDf, int N) {
    int i = blockIdx.x * 256 + threadIdx.x;
    if (i < N) {
        int a = degO[i]; nSf[i] = rsqrtf((float)(a > 1 ? a : 1));
        int b = degI[i]; nDf[i] = rsqrtf((float)(b > 1 ? b : 1));
    }
}

// ---------------- prefix scan (1024 elems / block) ----------------
__global__ void k_blocksum(const int* __restrict__ deg, int* __restrict__ bsum, int N) {
    __shared__ int sh[256];
    int base = blockIdx.x * 1024;
    int s = 0;
    for (int i = threadIdx.x; i < 1024; i += 256) {
        int idx = base + i;
        s += (idx < N) ? deg[idx] : 0;
    }
    sh[threadIdx.x] = s; __syncthreads();
    for (int off = 128; off > 0; off >>= 1) {
        if (threadIdx.x < off) sh[threadIdx.x] += sh[threadIdx.x + off];
        __syncthreads();
    }
    if (threadIdx.x == 0) bsum[blockIdx.x] = sh[0];
}

__global__ void k_scan_bsums(const int* __restrict__ bsum, int* __restrict__ boffs, int nb) {
    if (blockIdx.x == 0 && threadIdx.x == 0) {
        int run = 0;
        for (int i = 0; i < nb; ++i) { boffs[i] = run; run += bsum[i]; }
    }
}

__global__ void k_blockscan(const int* __restrict__ deg, const int* __restrict__ boffs,
                            int* __restrict__ rowptr, int* __restrict__ cursor, int N) {
    __shared__ int sh[256];
    int base = blockIdx.x * 1024;
    int i0 = base + threadIdx.x * 4;
    int v[4]; int tot = 0;
#pragma unroll
    for (int r = 0; r < 4; ++r) {
        int idx = i0 + r;
        v[r] = (idx < N) ? deg[idx] : 0;
        tot += v[r];
    }
    sh[threadIdx.x] = tot; __syncthreads();
    for (int off = 1; off < 256; off <<= 1) {
        int t = (threadIdx.x >= off) ? sh[threadIdx.x - off] : 0;
        __syncthreads();
        sh[threadIdx.x] += t;
        __syncthreads();
    }
    int run = sh[threadIdx.x] - tot + boffs[blockIdx.x];
#pragma unroll
    for (int r = 0; r < 4; ++r) {
        int idx = i0 + r;
        if (idx < N) { rowptr[idx] = run; cursor[idx] = run; }
        run += v[r];
    }
}

__global__ void k_fill2(const int* __restrict__ src, const int* __restrict__ dst,
                        int* __restrict__ cursor, int* __restrict__ col, int E) {
    int stride = gridDim.x * blockDim.x;
    for (int i = blockIdx.x * blockDim.x + threadIdx.x; i < E; i += stride) {
        int pos = atomicAdd(&cursor[dst[i]], 1);
        col[pos] = src[i];
    }
}

// -------- wave-per-node bf16 gather: out = relu(sum*nD + bias) (fp32) --------
// EDGESCALE: multiply each neighbor row by nSf[s] (P un-normalized).
template<int DOUT, bool EDGESCALE>
__global__ void __launch_bounds__(256) k_gatherw_b(
        const int* __restrict__ rowptr, const int* __restrict__ col,
        const int* __restrict__ degI, const float* __restrict__ nSf,
        const float* __restrict__ nDf, const ushort_t* __restrict__ projbf,
        const float* __restrict__ bias, float* __restrict__ out, int N) {
    constexpr int CH  = DOUT / 8;      // uint4 chunks (8 bf16)
    constexpr int EPW = 64 / CH;       // parallel edge slots
    int wid = blockIdx.x * 4 + (threadIdx.x >> 6);
    if (wid >= N) return;
    int lane = threadIdx.x & 63;
    int c = lane % CH;
    int e = lane / CH;
    int beg = rowptr[wid];
    int dg  = degI[wid];
    float acc[8];
#pragma unroll
    for (int j = 0; j < 8; ++j) acc[j] = 0.f;
    for (int i = e; i < dg; i += EPW) {
        int s = col[beg + i];
        uint4 v = *(const uint4*)(projbf + (size_t)s * DOUT + c * 8);
        if (EDGESCALE) {
            float ns = nSf[s];
            acc[0] = fmaf(ns, BFLO(v.x), acc[0]);
            acc[1] = fmaf(ns, BFHI(v.x), acc[1]);
            acc[2] = fmaf(ns, BFLO(v.y), acc[2]);
            acc[3] = fmaf(ns, BFHI(v.y), acc[3]);
            acc[4] = fmaf(ns, BFLO(v.z), acc[4]);
            acc[5] = fmaf(ns, BFHI(v.z), acc[5]);
            acc[6] = fmaf(ns, BFLO(v.w), acc[6]);
            acc[7] = fmaf(ns, BFHI(v.w), acc[7]);
        } else {
            acc[0] += BFLO(v.x); acc[1] += BFHI(v.x);
            acc[2] += BFLO(v.y); acc[3] += BFHI(v.y);
            acc[4] += BFLO(v.z); acc[5] += BFHI(v.z);
            acc[6] += BFLO(v.w); acc[7] += BFHI(v.w);
        }
    }
#pragma unroll
    for (int m = CH; m < 64; m <<= 1) {
#pragma unroll
        for (int j = 0; j < 8; ++j) acc[j] += __shfl_xor(acc[j], m, 64);
    }
    if (e == 0) {
        float nm = nDf[wid];
        const float* bp = bias + c * 8;
        float o[8];
#pragma unroll
        for (int j = 0; j < 8; ++j) o[j] = fmaxf(fmaf(acc[j], nm, bp[j]), 0.f);
        float* dstp = out + (size_t)wid * DOUT + c * 8;
        *(float4*)(dstp)     = make_float4(o[0], o[1], o[2], o[3]);
        *(float4*)(dstp + 4) = make_float4(o[4], o[5], o[6], o[7]);
    }
}

// -------- wave-per-node fp32 gather, DOUT=16 ---------------------------------
// MODE 0: out = sum (plain).  MODE 1: out = relu(sum*nD + bias) * nS  (t4 prep)
template<int MODE>
__global__ void __launch_bounds__(256) k_gatherw_f16d(
        const int* __restrict__ rowptr, const int* __restrict__ col,
        const int* __restrict__ degI, const float* __restrict__ nSf,
        const float* __restrict__ nDf, const float* __restrict__ proj,
        const float* __restrict__ bias, float* __restrict__ out, int N) {
    constexpr int CH  = 4;             // float4 chunks (16 floats)
    constexpr int EPW = 16;
    int wid = blockIdx.x * 4 + (threadIdx.x >> 6);
    if (wid >= N) return;
    int lane = threadIdx.x & 63;
    int c = lane & 3;
    int e = lane >> 2;
    int beg = rowptr[wid];
    int dg  = degI[wid];
    float4 a = make_float4(0.f, 0.f, 0.f, 0.f);
    for (int i = e; i < dg; i += EPW) {
        int s = col[beg + i];
        float4 v = *(const float4*)(proj + (size_t)s * 16 + c * 4);
        a.x += v.x; a.y += v.y; a.z += v.z; a.w += v.w;
    }
#pragma unroll
    for (int m = CH; m < 64; m <<= 1) {
        a.x += __shfl_xor(a.x, m, 64);
        a.y += __shfl_xor(a.y, m, 64);
        a.z += __shfl_xor(a.z, m, 64);
        a.w += __shfl_xor(a.w, m, 64);
    }
    if (e == 0) {
        float4 o;
        if (MODE == 1) {
            float nm = nDf[wid];
            float4 b = *(const float4*)(bias + c * 4);
            o.x = fmaxf(fmaf(a.x, nm, b.x), 0.f);
            o.y = fmaxf(fmaf(a.y, nm, b.y), 0.f);
            o.z = fmaxf(fmaf(a.z, nm, b.z), 0.f);
            o.w = fmaxf(fmaf(a.w, nm, b.w), 0.f);
            float ns = nSf[wid];
            o.x *= ns; o.y *= ns; o.z *= ns; o.w *= ns;
        } else {
            o = a;
        }
        *(float4*)(out + (size_t)wid * 16 + c * 4) = o;
    }
}

static inline int cdiv(long a, int b) { return (int)((a + b - 1) / b); }

extern "C" void kernel_launch(void* const* d_in, const int* in_sizes, int n_in,
                              void* d_out, int out_size, void* d_ws, size_t ws_size,
                              hipStream_t stream) {
    const float* x   = (const float*)d_in[0];
    const int*   src = (const int*)d_in[1];
    const int*   dst = (const int*)d_in[2];
    const float* W1 = (const float*)d_in[3];  const float* b1 = (const float*)d_in[4];
    const float* W2 = (const float*)d_in[5];  const float* b2 = (const float*)d_in[6];
    const float* W3 = (const float*)d_in[7];  const float* b3 = (const float*)d_in[8];
    const float* W4 = (const float*)d_in[9];  const float* b4 = (const float*)d_in[10];

    const int N = in_sizes[0] / 256;
    const int E = in_sizes[1];

    // ---- workspace layout ----
    int* ws_i = (int*)d_ws;
    int* degO   = ws_i;                       // [N]
    int* degI   = ws_i + N;                   // [N]
    int* rowptr = ws_i + 2 * (size_t)N;       // [N]
    int* col    = ws_i + 3 * (size_t)N;       // [E]
    float* nSf  = (float*)(ws_i + 3 * (size_t)N + E);  // [N]
    float* nDf  = nSf + N;                    // [N]
    float* projb = nDf + N;                   // N*64 f32 region (P1 bf16 N*128 / P2 bf16 N*64 / P3,agg4 f32 N*16)
    float* hbuf  = projb + (size_t)N * 64;    // N*128 f32 (h1 / h2 / t4)
    ushort_t* projbf = (ushort_t*)projb;
    // CSR-build scratch aliased into hbuf (dead before first hbuf write)
    int* bsum   = (int*)hbuf;                 // [<=4096]
    int* boffs  = bsum + 4096;                // [<=4096]
    int* cursor = bsum + 16384;               // [N]

    int nb = (N + 1023) / 1024;
    int PB = cdiv(N, 64);
    int G5 = cdiv(PB, 3);
    int HTH = (2 * G5) * 256;
    int GW = cdiv(N, 4);   // wave-per-node grids

    // ---- combined: histogram || proj1 (bf16, un-normalized) ----
    hipMemsetAsync(degO, 0, 2 * (size_t)N * sizeof(int), stream);
    k_comb<256, 128, 64, 32><<<5 * G5, 256, 0, stream>>>(
        x, W1, projbf, N, src, dst, degO, degI, E, PB, HTH);

    // ---- norms + CSR (cursor dual-stored; no memcpy node) ----
    k_prep<<<cdiv(N, 256), 256, 0, stream>>>(degO, degI, nSf, nDf, N);
    k_blocksum<<<nb, 256, 0, stream>>>(degI, bsum, N);
    k_scan_bsums<<<1, 64, 0, stream>>>(bsum, boffs, nb);
    k_blockscan<<<nb, 256, 0, stream>>>(degI, boffs, rowptr, cursor, N);
    k_fill2<<<2048, 256, 0, stream>>>(src, dst, cursor, col, E);

    // ---- layer 1 aggregate: bf16 wave-gather w/ per-edge nS -> hbuf (h1) ----
    k_gatherw_b<128, true><<<GW, 256, 0, stream>>>(
        rowptr, col, degI, nSf, nDf, projbf, b1, hbuf, N);

    // ---- layer 2: proj (h1@W2)*nS -> P2 bf16; wave-gather -> hbuf (h2) ----
    k_proj_gl2b<128, 64, 64, 32><<<cdiv(N, 64), 256, 0, stream>>>(
        hbuf, nSf, W2, projbf, N);
    k_gatherw_b<64, false><<<GW, 256, 0, stream>>>(
        rowptr, col, degI, nSf, nDf, projbf, b2, hbuf, N);

    // ---- layer 3: proj -> P3 f32 (projb); wave-gather (relu+nD+b3, *nS) -> hbuf (t4) ----
    k_proj_lds<64, 16, 1, 64, 0><<<cdiv(N, 64), 256, 0, stream>>>(
        hbuf, nSf, W3, nullptr, projb, N);
    k_gatherw_f16d<1><<<GW, 256, 0, stream>>>(
        rowptr, col, degI, nSf, nDf, projb, b3, hbuf, N);

    // ---- layer 4 (aggregate-first): wave-gather t4 -> projb; (agg@W4)*nD+b4 -> out ----
    k_gatherw_f16d<0><<<GW, 256, 0, stream>>>(
        rowptr, col, degI, nSf, nDf, hbuf, nullptr, projb, N);
    k_proj_lds<16, 40, 2, 16, 1><<<cdiv(N, 50), 256, 0, stream>>>(
        projb, nDf, W4, b4, (float*)d_out, N);
}

// Round 9
// 385.155 us; speedup vs baseline: 1.3658x; 1.3658x over previous
//
#include <hip/hip_runtime.h>

// GCN 4 layers: N=100000, E=1600000, dims 256->128->64->16->40.
//  k_comb : blocks 3:2 -> {proj1 P1=x@W1 (bf16, un-normalized)} || {hist + edge-rank}
//  CSR    : fused blocksum+norms -> scan -> rowptr -> k_fill3 (NO atomics: rank-based)
//  L1 agg : bf16 gather (thread per node-chunk) w/ per-edge nS[s], fused nD+b1+ReLU
//  L2     : proj (global_load_lds staged, bf16 out w/ nS applied) -> bf16 gather
//  L3     : small proj -> fp32 gather (fused relu+nD+b3, then *nS for L4)
//  L4     : aggregate-first: fp32 gather t4, fused GEMM (agg@W4)*nD+b4 -> out

typedef unsigned short ushort_t;

__device__ __forceinline__ void gload_lds16(const float4* g, float4* l) {
    __builtin_amdgcn_global_load_lds(
        (const __attribute__((address_space(1))) void*)g,
        (__attribute__((address_space(3))) void*)l, 16, 0, 0);
}

__device__ __forceinline__ ushort_t f2bf(float f) {
    unsigned u = __float_as_uint(f);
    u += 0x7FFFu + ((u >> 16) & 1u);          // RNE
    return (ushort_t)(u >> 16);
}
#define BFLO(u) __uint_as_float((u) << 16)
#define BFHI(u) __uint_as_float((u) & 0xffff0000u)

// ---------------- shared proj GEMM body (global_load_lds staged x and W) ------
template<int DIN, int DOUT, int RB, int KT, typename EPI>
__device__ __forceinline__ void proj_body(
        const float* __restrict__ in, const float* __restrict__ W,
        int N, int n0, float4* __restrict__ wlds, float4* __restrict__ xlds,
        EPI&& epi) {
    constexpr int CG  = DOUT / 4;
    constexpr int RPP = 256 / CG;
    constexpr int R4  = RB / RPP;
    constexpr int K4T = KT / 4;
    constexpr int NKT = DIN / KT;
    constexpr int XTILE = RB * K4T;
    constexpr int WTILE = KT * CG;
    static_assert(RPP * CG == 256, "full block");
    static_assert((K4T & (K4T - 1)) == 0, "pow2 swizzle");
    static_assert(XTILE % 256 == 0 && WTILE % 256 == 0, "stage granularity");

    const int tid  = threadIdx.x;
    const int wave = tid >> 6;
    const int lane = tid & 63;
    const int rp   = tid / CG;
    const int cg   = tid - rp * CG;

    float4 acc[R4];
#pragma unroll
    for (int r = 0; r < R4; ++r) acc[r] = make_float4(0.f, 0.f, 0.f, 0.f);

    for (int kt = 0; kt < NKT; ++kt) {
        const float4* wsrc = (const float4*)(W + (size_t)kt * KT * DOUT);
#pragma unroll
        for (int j = 0; j < WTILE / 256; ++j) {
            int base = j * 256 + wave * 64;
            gload_lds16(wsrc + base + lane, &wlds[base]);
        }
#pragma unroll
        for (int j = 0; j < XTILE / 256; ++j) {
            int base = j * 256 + wave * 64;
            int fi   = base + lane;
            int row  = fi / K4T;
            int k4   = fi - row * K4T;
            int k4s  = k4 ^ (row & (K4T - 1));
            int grow = n0 + row; if (grow >= N) grow = N - 1;
            const float4* gsrc = (const float4*)(in + (size_t)grow * DIN) + kt * K4T + k4s;
            gload_lds16(gsrc, &xlds[base]);
        }
        __syncthreads();
#pragma unroll 2
        for (int k4 = 0; k4 < K4T; ++k4) {
            float4 w0 = wlds[(k4 * 4 + 0) * CG + cg];
            float4 w1 = wlds[(k4 * 4 + 1) * CG + cg];
            float4 w2 = wlds[(k4 * 4 + 2) * CG + cg];
            float4 w3 = wlds[(k4 * 4 + 3) * CG + cg];
#pragma unroll
            for (int r = 0; r < R4; ++r) {
                int row = rp + r * RPP;
                float4 xv = xlds[row * K4T + (k4 ^ (row & (K4T - 1)))];
                acc[r].x = fmaf(xv.x, w0.x, acc[r].x);
                acc[r].y = fmaf(xv.x, w0.y, acc[r].y);
                acc[r].z = fmaf(xv.x, w0.z, acc[r].z);
                acc[r].w = fmaf(xv.x, w0.w, acc[r].w);
                acc[r].x = fmaf(xv.y, w1.x, acc[r].x);
                acc[r].y = fmaf(xv.y, w1.y, acc[r].y);
                acc[r].z = fmaf(xv.y, w1.z, acc[r].z);
                acc[r].w = fmaf(xv.y, w1.w, acc[r].w);
                acc[r].x = fmaf(xv.z, w2.x, acc[r].x);
                acc[r].y = fmaf(xv.z, w2.y, acc[r].y);
                acc[r].z = fmaf(xv.z, w2.z, acc[r].z);
                acc[r].w = fmaf(xv.z, w2.w, acc[r].w);
                acc[r].x = fmaf(xv.w, w3.x, acc[r].x);
                acc[r].y = fmaf(xv.w, w3.y, acc[r].y);
                acc[r].z = fmaf(xv.w, w3.z, acc[r].z);
                acc[r].w = fmaf(xv.w, w3.w, acc[r].w);
            }
        }
        __syncthreads();
    }
    epi(acc, rp, cg);
}

// ------ combined: proj1 (bf16, un-normalized) || histogram + edge rank -------
template<int DIN, int DOUT, int RB, int KT>
__global__ void __launch_bounds__(256) k_comb(
        const float* __restrict__ x, const float* __restrict__ W,
        ushort_t* __restrict__ outbf, int N,
        const int* __restrict__ src, const int* __restrict__ dst,
        int* __restrict__ degO, int* __restrict__ degI,
        int* __restrict__ rank, int E, int PB, int HTH) {
    constexpr int CG  = DOUT / 4;
    constexpr int RPP = 256 / CG;
    constexpr int R4  = RB / RPP;
    constexpr int K4T = KT / 4;
    __shared__ float4 wlds[KT * CG];
    __shared__ float4 xlds[RB * K4T];

    int bid = blockIdx.x, g = bid / 5, r = bid - g * 5;
    if (r >= 3) {
        // histogram role: count degrees AND record each edge's rank in its dst row
        int i = (g * 2 + (r - 3)) * 256 + (int)threadIdx.x;
        for (; i < E; i += HTH) {
            atomicAdd(&degO[src[i]], 1);
            rank[i] = atomicAdd(&degI[dst[i]], 1);
        }
        return;
    }
    int pidx = g * 3 + r;
    if (pidx >= PB) return;
    int n0 = pidx * RB;
    proj_body<DIN, DOUT, RB, KT>(x, W, N, n0, wlds, xlds,
        [&](float4 (&acc)[R4], int rp, int cg) {
#pragma unroll
            for (int rr = 0; rr < R4; ++rr) {
                int n = n0 + rp + rr * RPP;
                if (n < N) {
                    ushort4 s;
                    s.x = f2bf(acc[rr].x); s.y = f2bf(acc[rr].y);
                    s.z = f2bf(acc[rr].z); s.w = f2bf(acc[rr].w);
                    *(ushort4*)(outbf + (size_t)n * DOUT + cg * 4) = s;
                }
            }
        });
}

// ---------------- proj, bf16 out with *nrm[n] applied -------------------------
template<int DIN, int DOUT, int RB, int KT>
__global__ void __launch_bounds__(256) k_proj_gl2b(
        const float* __restrict__ in, const float* __restrict__ nrm,
        const float* __restrict__ W, ushort_t* __restrict__ outbf, int N) {
    constexpr int CG  = DOUT / 4;
    constexpr int RPP = 256 / CG;
    constexpr int R4  = RB / RPP;
    constexpr int K4T = KT / 4;
    __shared__ float4 wlds[KT * CG];
    __shared__ float4 xlds[RB * K4T];
    int n0 = blockIdx.x * RB;
    proj_body<DIN, DOUT, RB, KT>(in, W, N, n0, wlds, xlds,
        [&](float4 (&acc)[R4], int rp, int cg) {
#pragma unroll
            for (int rr = 0; rr < R4; ++rr) {
                int n = n0 + rp + rr * RPP;
                if (n < N) {
                    float nm = nrm[n];
                    ushort4 s;
                    s.x = f2bf(acc[rr].x * nm); s.y = f2bf(acc[rr].y * nm);
                    s.z = f2bf(acc[rr].z * nm); s.w = f2bf(acc[rr].w * nm);
                    *(ushort4*)(outbf + (size_t)n * DOUT + cg * 4) = s;
                }
            }
        });
}

// ---------------- small proj (global-x), EPI 0: *nrm; 1: *nrm+bias -----------
template<int DIN, int DOUT, int R4, int KT, int EPI>
__global__ void __launch_bounds__(256) k_proj_lds(
        const float* __restrict__ in, const float* __restrict__ nrm,
        const float* __restrict__ W, const float* __restrict__ bias,
        float* __restrict__ out, int N) {
    constexpr int CG  = DOUT / 4;
    constexpr int RPP = 256 / CG;
    constexpr int RB  = RPP * R4;
    constexpr int NKT = DIN / KT;
    __shared__ float4 wlds[KT * CG];

    int tid = threadIdx.x;
    int rp  = tid / CG;
    int cg  = tid - rp * CG;
    bool active = (rp < RPP);
    int n0 = blockIdx.x * RB;

    int nrow[R4];
    const float4* xr[R4];
#pragma unroll
    for (int r = 0; r < R4; ++r) {
        int n = n0 + rp + r * RPP;
        nrow[r] = n;
        int nc = n < N ? n : N - 1;
        xr[r] = (const float4*)(in + (size_t)nc * DIN);
    }
    float4 acc[R4];
#pragma unroll
    for (int r = 0; r < R4; ++r) acc[r] = make_float4(0.f, 0.f, 0.f, 0.f);

    for (int kt = 0; kt < NKT; ++kt) {
        const float4* wsrc = (const float4*)(W + (size_t)kt * KT * DOUT);
        for (int i = tid; i < KT * CG; i += 256) wlds[i] = wsrc[i];
        __syncthreads();
        if (active) {
#pragma unroll 2
            for (int k4 = 0; k4 < KT / 4; ++k4) {
                float4 w0 = wlds[(k4 * 4 + 0) * CG + cg];
                float4 w1 = wlds[(k4 * 4 + 1) * CG + cg];
                float4 w2 = wlds[(k4 * 4 + 2) * CG + cg];
                float4 w3 = wlds[(k4 * 4 + 3) * CG + cg];
#pragma unroll
                for (int r = 0; r < R4; ++r) {
                    float4 xv = xr[r][kt * (KT / 4) + k4];
                    acc[r].x = fmaf(xv.x, w0.x, acc[r].x);
                    acc[r].y = fmaf(xv.x, w0.y, acc[r].y);
                    acc[r].z = fmaf(xv.x, w0.z, acc[r].z);
                    acc[r].w = fmaf(xv.x, w0.w, acc[r].w);
                    acc[r].x = fmaf(xv.y, w1.x, acc[r].x);
                    acc[r].y = fmaf(xv.y, w1.y, acc[r].y);
                    acc[r].z = fmaf(xv.y, w1.z, acc[r].z);
                    acc[r].w = fmaf(xv.y, w1.w, acc[r].w);
                    acc[r].x = fmaf(xv.z, w2.x, acc[r].x);
                    acc[r].y = fmaf(xv.z, w2.y, acc[r].y);
                    acc[r].z = fmaf(xv.z, w2.z, acc[r].z);
                    acc[r].w = fmaf(xv.z, w2.w, acc[r].w);
                    acc[r].x = fmaf(xv.w, w3.x, acc[r].x);
                    acc[r].y = fmaf(xv.w, w3.y, acc[r].y);
                    acc[r].z = fmaf(xv.w, w3.z, acc[r].z);
                    acc[r].w = fmaf(xv.w, w3.w, acc[r].w);
                }
            }
        }
        __syncthreads();
    }
    if (active) {
#pragma unroll
        for (int r = 0; r < R4; ++r) {
            int n = nrow[r];
            if (n < N) {
                float nm = nrm[n];
                float4 o;
                if (EPI == 0) {
                    o = make_float4(acc[r].x * nm, acc[r].y * nm,
                                    acc[r].z * nm, acc[r].w * nm);
                } else {
                    float4 b = *(const float4*)(bias + cg * 4);
                    o.x = fmaf(acc[r].x, nm, b.x);
                    o.y = fmaf(acc[r].y, nm, b.y);
                    o.z = fmaf(acc[r].z, nm, b.z);
                    o.w = fmaf(acc[r].w, nm, b.w);
                }
                *(float4*)(out + (size_t)n * DOUT + cg * 4) = o;
            }
        }
    }
}

// -------- fused: per-block degI sums (for scan) + nSf/nDf precompute ---------
__global__ void k_blocksum(const int* __restrict__ degI, const int* __restrict__ degO,
                           int* __restrict__ bsum, float* __restrict__ nSf,
                           float* __restrict__ nDf, int N) {
    __shared__ int sh[256];
    int base = blockIdx.x * 1024;
    int s = 0;
    for (int i = threadIdx.x; i < 1024; i += 256) {
        int idx = base + i;
        if (idx < N) {
            int d = degI[idx];
            s += d;
            nDf[idx] = rsqrtf((float)(d > 1 ? d : 1));
            int a = degO[idx];
            nSf[idx] = rsqrtf((float)(a > 1 ? a : 1));
        }
    }
    sh[threadIdx.x] = s; __syncthreads();
    for (int off = 128; off > 0; off >>= 1) {
        if (threadIdx.x < off) sh[threadIdx.x] += sh[threadIdx.x + off];
        __syncthreads();
    }
    if (threadIdx.x == 0) bsum[blockIdx.x] = sh[0];
}

__global__ void k_scan_bsums(const int* __restrict__ bsum, int* __restrict__ boffs, int nb) {
    if (blockIdx.x == 0 && threadIdx.x == 0) {
        int run = 0;
        for (int i = 0; i < nb; ++i) { boffs[i] = run; run += bsum[i]; }
    }
}

__global__ void k_blockscan(const int* __restrict__ deg, const int* __restrict__ boffs,
                            int* __restrict__ rowptr, int N) {
    __shared__ int sh[256];
    int base = blockIdx.x * 1024;
    int i0 = base + threadIdx.x * 4;
    int v[4]; int tot = 0;
#pragma unroll
    for (int r = 0; r < 4; ++r) {
        int idx = i0 + r;
        v[r] = (idx < N) ? deg[idx] : 0;
        tot += v[r];
    }
    sh[threadIdx.x] = tot; __syncthreads();
    for (int off = 1; off < 256; off <<= 1) {
        int t = (threadIdx.x >= off) ? sh[threadIdx.x - off] : 0;
        __syncthreads();
        sh[threadIdx.x] += t;
        __syncthreads();
    }
    int run = sh[threadIdx.x] - tot + boffs[blockIdx.x];
#pragma unroll
    for (int r = 0; r < 4; ++r) {
        int idx = i0 + r;
        if (idx < N) rowptr[idx] = run;
        run += v[r];
    }
}

// ---------- atomic-free CSR fill: col[rowptr[dst]+rank] = src ----------------
__global__ void k_fill3(const int* __restrict__ src, const int* __restrict__ dst,
                        const int* __restrict__ rank, const int* __restrict__ rowptr,
                        int* __restrict__ col, int E) {
    int stride = gridDim.x * blockDim.x;
    for (int i = blockIdx.x * blockDim.x + threadIdx.x; i < E; i += stride) {
        col[rowptr[dst[i]] + rank[i]] = src[i];
    }
}

// -------- bf16 gather, thread per (node, 8-col chunk): relu(sum*nD+b) --------
// EDGESCALE: multiply each neighbor row by nSf[s] (P un-normalized).
template<int DOUT, bool EDGESCALE>
__global__ void __launch_bounds__(256) k_gather_b(
        const int* __restrict__ rowptr, const int* __restrict__ col,
        const int* __restrict__ degI, const float* __restrict__ nSf,
        const float* __restrict__ nDf, const ushort_t* __restrict__ projbf,
        const float* __restrict__ bias, float* __restrict__ out, int N) {
    constexpr int CGB = DOUT / 8;
    long t = blockIdx.x * 256L + threadIdx.x;
    if (t >= (long)N * CGB) return;
    int n  = (int)(t / CGB);
    int cb = (int)(t - (long)n * CGB);
    int beg = rowptr[n];
    int dg  = degI[n];
    float acc[8];
#pragma unroll
    for (int k = 0; k < 8; ++k) acc[k] = 0.f;
    int i = 0;
    for (; i + 2 <= dg; i += 2) {
        int s0 = col[beg + i];
        int s1 = col[beg + i + 1];
        uint4 v0 = *(const uint4*)(projbf + (size_t)s0 * DOUT + cb * 8);
        uint4 v1 = *(const uint4*)(projbf + (size_t)s1 * DOUT + cb * 8);
        float ns0 = EDGESCALE ? nSf[s0] : 1.f;
        float ns1 = EDGESCALE ? nSf[s1] : 1.f;
        if (EDGESCALE) {
            acc[0] = fmaf(ns0, BFLO(v0.x), acc[0]);
            acc[1] = fmaf(ns0, BFHI(v0.x), acc[1]);
            acc[2] = fmaf(ns0, BFLO(v0.y), acc[2]);
            acc[3] = fmaf(ns0, BFHI(v0.y), acc[3]);
            acc[4] = fmaf(ns0, BFLO(v0.z), acc[4]);
            acc[5] = fmaf(ns0, BFHI(v0.z), acc[5]);
            acc[6] = fmaf(ns0, BFLO(v0.w), acc[6]);
            acc[7] = fmaf(ns0, BFHI(v0.w), acc[7]);
            acc[0] = fmaf(ns1, BFLO(v1.x), acc[0]);
            acc[1] = fmaf(ns1, BFHI(v1.x), acc[1]);
            acc[2] = fmaf(ns1, BFLO(v1.y), acc[2]);
            acc[3] = fmaf(ns1, BFHI(v1.y), acc[3]);
            acc[4] = fmaf(ns1, BFLO(v1.z), acc[4]);
            acc[5] = fmaf(ns1, BFHI(v1.z), acc[5]);
            acc[6] = fmaf(ns1, BFLO(v1.w), acc[6]);
            acc[7] = fmaf(ns1, BFHI(v1.w), acc[7]);
        } else {
            acc[0] += BFLO(v0.x) + BFLO(v1.x);
            acc[1] += BFHI(v0.x) + BFHI(v1.x);
            acc[2] += BFLO(v0.y) + BFLO(v1.y);
            acc[3] += BFHI(v0.y) + BFHI(v1.y);
            acc[4] += BFLO(v0.z) + BFLO(v1.z);
            acc[5] += BFHI(v0.z) + BFHI(v1.z);
            acc[6] += BFLO(v0.w) + BFLO(v1.w);
            acc[7] += BFHI(v0.w) + BFHI(v1.w);
        }
    }
    if (i < dg) {
        int s0 = col[beg + i];
        uint4 v0 = *(const uint4*)(projbf + (size_t)s0 * DOUT + cb * 8);
        float ns0 = EDGESCALE ? nSf[s0] : 1.f;
        acc[0] = fmaf(ns0, BFLO(v0.x), acc[0]);
        acc[1] = fmaf(ns0, BFHI(v0.x), acc[1]);
        acc[2] = fmaf(ns0, BFLO(v0.y), acc[2]);
        acc[3] = fmaf(ns0, BFHI(v0.y), acc[3]);
        acc[4] = fmaf(ns0, BFLO(v0.z), acc[4]);
        acc[5] = fmaf(ns0, BFHI(v0.z), acc[5]);
        acc[6] = fmaf(ns0, BFLO(v0.w), acc[6]);
        acc[7] = fmaf(ns0, BFHI(v0.w), acc[7]);
    }
    float nm = nDf[n];
    const float* bp = bias + cb * 8;
    float o[8];
#pragma unroll
    for (int k = 0; k < 8; ++k) o[k] = fmaxf(fmaf(acc[k], nm, bp[k]), 0.f);
    float* dstp = out + (size_t)n * DOUT + cb * 8;
    *(float4*)(dstp)     = make_float4(o[0], o[1], o[2], o[3]);
    *(float4*)(dstp + 4) = make_float4(o[4], o[5], o[6], o[7]);
}

// ---------------- fp32 CSR gather + fused epilogue ----------------
template<int DOUT, bool RELU, bool NORMBIAS, bool SCALESRC>
__global__ void __launch_bounds__(256) k_gather(
        const int* __restrict__ rowptr, const int* __restrict__ col,
        const int* __restrict__ degI, const float* __restrict__ nSf,
        const float* __restrict__ nDf, const float* __restrict__ proj,
        const float* __restrict__ bias, float* __restrict__ out, int N) {
    constexpr int CG = DOUT / 4;
    long t = blockIdx.x * 256L + threadIdx.x;
    if (t >= (long)N * CG) return;
    int n  = (int)(t / CG);
    int cg = (int)(t - (long)n * CG);
    int beg = rowptr[n];
    int dg  = degI[n];
    float4 a0 = make_float4(0.f, 0.f, 0.f, 0.f);
    float4 a1 = make_float4(0.f, 0.f, 0.f, 0.f);
    float4 a2 = make_float4(0.f, 0.f, 0.f, 0.f);
    float4 a3 = make_float4(0.f, 0.f, 0.f, 0.f);
    int i = 0;
    for (; i + 4 <= dg; i += 4) {
        int s0 = col[beg + i];
        int s1 = col[beg + i + 1];
        int s2 = col[beg + i + 2];
        int s3 = col[beg + i + 3];
        float4 v0 = *(const float4*)(proj + (size_t)s0 * DOUT + cg * 4);
        float4 v1 = *(const float4*)(proj + (size_t)s1 * DOUT + cg * 4);
        float4 v2 = *(const float4*)(proj + (size_t)s2 * DOUT + cg * 4);
        float4 v3 = *(const float4*)(proj + (size_t)s3 * DOUT + cg * 4);
        a0.x += v0.x; a0.y += v0.y; a0.z += v0.z; a0.w += v0.w;
        a1.x += v1.x; a1.y += v1.y; a1.z += v1.z; a1.w += v1.w;
        a2.x += v2.x; a2.y += v2.y; a2.z += v2.z; a2.w += v2.w;
        a3.x += v3.x; a3.y += v3.y; a3.z += v3.z; a3.w += v3.w;
    }
    for (; i < dg; ++i) {
        int s0 = col[beg + i];
        float4 v0 = *(const float4*)(proj + (size_t)s0 * DOUT + cg * 4);
        a0.x += v0.x; a0.y += v0.y; a0.z += v0.z; a0.w += v0.w;
    }
    float4 o = make_float4(a0.x + a1.x + a2.x + a3.x,
                           a0.y + a1.y + a2.y + a3.y,
                           a0.z + a1.z + a2.z + a3.z,
                           a0.w + a1.w + a2.w + a3.w);
    if (NORMBIAS) {
        float nm = nDf[n];
        float4 b = *(const float4*)(bias + cg * 4);
        o.x = fmaf(o.x, nm, b.x);
        o.y = fmaf(o.y, nm, b.y);
        o.z = fmaf(o.z, nm, b.z);
        o.w = fmaf(o.w, nm, b.w);
    }
    if (RELU) {
        o.x = fmaxf(o.x, 0.f); o.y = fmaxf(o.y, 0.f);
        o.z = fmaxf(o.z, 0.f); o.w = fmaxf(o.w, 0.f);
    }
    if (SCALESRC) {
        float ns = nSf[n];
        o.x *= ns; o.y *= ns; o.z *= ns; o.w *= ns;
    }
    *(float4*)(out + (size_t)n * DOUT + cg * 4) = o;
}

static inline int cdiv(long a, int b) { return (int)((a + b - 1) / b); }

extern "C" void kernel_launch(void* const* d_in, const int* in_sizes, int n_in,
                              void* d_out, int out_size, void* d_ws, size_t ws_size,
                              hipStream_t stream) {
    const float* x   = (const float*)d_in[0];
    const int*   src = (const int*)d_in[1];
    const int*   dst = (const int*)d_in[2];
    const float* W1 = (const float*)d_in[3];  const float* b1 = (const float*)d_in[4];
    const float* W2 = (const float*)d_in[5];  const float* b2 = (const float*)d_in[6];
    const float* W3 = (const float*)d_in[7];  const float* b3 = (const float*)d_in[8];
    const float* W4 = (const float*)d_in[9];  const float* b4 = (const float*)d_in[10];

    const int N = in_sizes[0] / 256;
    const int E = in_sizes[1];

    // ---- workspace layout ----
    int* ws_i = (int*)d_ws;
    int* degO   = ws_i;                       // [N]
    int* degI   = ws_i + N;                   // [N]
    int* rowptr = ws_i + 2 * (size_t)N;       // [N]
    int* col    = ws_i + 3 * (size_t)N;       // [E]
    int* rank   = ws_i + 3 * (size_t)N + E;   // [E]
    float* nSf  = (float*)(ws_i + 3 * (size_t)N + 2 * (size_t)E);  // [N]
    float* nDf  = nSf + N;                    // [N]
    float* projb = nDf + N;                   // N*64 f32 region (P1/P2 bf16, P3/agg4 f32)
    float* hbuf  = projb + (size_t)N * 64;    // N*128 f32 (h1 / h2 / t4)
    ushort_t* projbf = (ushort_t*)projb;
    // CSR-build scratch aliased into hbuf (dead before first hbuf write)
    int* bsum   = (int*)hbuf;                 // [<=4096]
    int* boffs  = bsum + 4096;                // [<=4096]

    int nb = (N + 1023) / 1024;
    int PB = cdiv(N, 64);
    int G5 = cdiv(PB, 3);
    int HTH = (2 * G5) * 256;

    // ---- combined: histogram+rank || proj1 (bf16, un-normalized) ----
    hipMemsetAsync(degO, 0, 2 * (size_t)N * sizeof(int), stream);
    k_comb<256, 128, 64, 32><<<5 * G5, 256, 0, stream>>>(
        x, W1, projbf, N, src, dst, degO, degI, rank, E, PB, HTH);

    // ---- norms + CSR (fused blocksum+prep; atomic-free fill) ----
    k_blocksum<<<nb, 256, 0, stream>>>(degI, degO, bsum, nSf, nDf, N);
    k_scan_bsums<<<1, 64, 0, stream>>>(bsum, boffs, nb);
    k_blockscan<<<nb, 256, 0, stream>>>(degI, boffs, rowptr, N);
    k_fill3<<<2048, 256, 0, stream>>>(src, dst, rank, rowptr, col, E);

    // ---- layer 1 aggregate: bf16 gather w/ per-edge nS -> hbuf (h1) ----
    k_gather_b<128, true><<<cdiv((long)N * 16, 256), 256, 0, stream>>>(
        rowptr, col, degI, nSf, nDf, projbf, b1, hbuf, N);

    // ---- layer 2: proj (h1@W2)*nS -> P2 bf16; gather -> hbuf (h2) ----
    k_proj_gl2b<128, 64, 64, 32><<<cdiv(N, 64), 256, 0, stream>>>(
        hbuf, nSf, W2, projbf, N);
    k_gather_b<64, false><<<cdiv((long)N * 8, 256), 256, 0, stream>>>(
        rowptr, col, degI, nSf, nDf, projbf, b2, hbuf, N);

    // ---- layer 3: proj -> P3 f32 (projb); gather (relu+nD+b3, *nS) -> hbuf (t4) ----
    k_proj_lds<64, 16, 1, 64, 0><<<cdiv(N, 64), 256, 0, stream>>>(
        hbuf, nSf, W3, nullptr, projb, N);
    k_gather<16, true, true, true><<<cdiv((long)N * 4, 256), 256, 0, stream>>>(
        rowptr, col, degI, nSf, nDf, projb, b3, hbuf, N);

    // ---- layer 4 (aggregate-first): gather t4 -> projb; (agg@W4)*nD+b4 -> out ----
    k_gather<16, false, false, false><<<cdiv((long)N * 4, 256), 256, 0, stream>>>(
        rowptr, col, degI, nSf, nDf, hbuf, nullptr, projb, N);
    k_proj_lds<16, 40, 2, 16, 1><<<cdiv(N, 50), 256, 0, stream>>>(
        projb, nDf, W4, b4, (float*)d_out, N);
}

// Round 10
// 377.921 us; speedup vs baseline: 1.3920x; 1.0191x over previous
//
#include <hip/hip_runtime.h>

// GCN 4 layers: N=100000, E=1600000, dims 256->128->64->16->40.
//  k_comb : blocks 4:1 -> {proj1 P1=x@W1 (bf16, un-normalized)} || {hist + edge-rank}
//  CSR    : fused blocksum+norms -> scan -> rowptr -> k_fill3 (NO atomics)
//  L1 agg : bf16 gather (4-edge unroll) w/ per-edge nS[s], fused nD+b1+ReLU
//  L2     : proj (bf16 P2 w/ nS) -> FUSED gather+h2+P3 GEMM (W3 in LDS, shfl row exchange)
//  L3     : fp32 gather P3 (fused relu+nD+b3, then *nS) -> t4
//  L4     : FUSED gather t4 + (agg@W4)*nD+b4 GEMM (W4 in LDS) -> out

typedef unsigned short ushort_t;

__device__ __forceinline__ void gload_lds16(const float4* g, float4* l) {
    __builtin_amdgcn_global_load_lds(
        (const __attribute__((address_space(1))) void*)g,
        (__attribute__((address_space(3))) void*)l, 16, 0, 0);
}

__device__ __forceinline__ ushort_t f2bf(float f) {
    unsigned u = __float_as_uint(f);
    u += 0x7FFFu + ((u >> 16) & 1u);          // RNE
    return (ushort_t)(u >> 16);
}
#define BFLO(u) __uint_as_float((u) << 16)
#define BFHI(u) __uint_as_float((u) & 0xffff0000u)

// ---------------- shared proj GEMM body (global_load_lds staged x and W) ------
template<int DIN, int DOUT, int RB, int KT, typename EPI>
__device__ __forceinline__ void proj_body(
        const float* __restrict__ in, const float* __restrict__ W,
        int N, int n0, float4* __restrict__ wlds, float4* __restrict__ xlds,
        EPI&& epi) {
    constexpr int CG  = DOUT / 4;
    constexpr int RPP = 256 / CG;
    constexpr int R4  = RB / RPP;
    constexpr int K4T = KT / 4;
    constexpr int NKT = DIN / KT;
    constexpr int XTILE = RB * K4T;
    constexpr int WTILE = KT * CG;
    static_assert(RPP * CG == 256, "full block");
    static_assert((K4T & (K4T - 1)) == 0, "pow2 swizzle");
    static_assert(XTILE % 256 == 0 && WTILE % 256 == 0, "stage granularity");

    const int tid  = threadIdx.x;
    const int wave = tid >> 6;
    const int lane = tid & 63;
    const int rp   = tid / CG;
    const int cg   = tid - rp * CG;

    float4 acc[R4];
#pragma unroll
    for (int r = 0; r < R4; ++r) acc[r] = make_float4(0.f, 0.f, 0.f, 0.f);

    for (int kt = 0; kt < NKT; ++kt) {
        const float4* wsrc = (const float4*)(W + (size_t)kt * KT * DOUT);
#pragma unroll
        for (int j = 0; j < WTILE / 256; ++j) {
            int base = j * 256 + wave * 64;
            gload_lds16(wsrc + base + lane, &wlds[base]);
        }
#pragma unroll
        for (int j = 0; j < XTILE / 256; ++j) {
            int base = j * 256 + wave * 64;
            int fi   = base + lane;
            int row  = fi / K4T;
            int k4   = fi - row * K4T;
            int k4s  = k4 ^ (row & (K4T - 1));
            int grow = n0 + row; if (grow >= N) grow = N - 1;
            const float4* gsrc = (const float4*)(in + (size_t)grow * DIN) + kt * K4T + k4s;
            gload_lds16(gsrc, &xlds[base]);
        }
        __syncthreads();
#pragma unroll 2
        for (int k4 = 0; k4 < K4T; ++k4) {
            float4 w0 = wlds[(k4 * 4 + 0) * CG + cg];
            float4 w1 = wlds[(k4 * 4 + 1) * CG + cg];
            float4 w2 = wlds[(k4 * 4 + 2) * CG + cg];
            float4 w3 = wlds[(k4 * 4 + 3) * CG + cg];
#pragma unroll
            for (int r = 0; r < R4; ++r) {
                int row = rp + r * RPP;
                float4 xv = xlds[row * K4T + (k4 ^ (row & (K4T - 1)))];
                acc[r].x = fmaf(xv.x, w0.x, acc[r].x);
                acc[r].y = fmaf(xv.x, w0.y, acc[r].y);
                acc[r].z = fmaf(xv.x, w0.z, acc[r].z);
                acc[r].w = fmaf(xv.x, w0.w, acc[r].w);
                acc[r].x = fmaf(xv.y, w1.x, acc[r].x);
                acc[r].y = fmaf(xv.y, w1.y, acc[r].y);
                acc[r].z = fmaf(xv.y, w1.z, acc[r].z);
                acc[r].w = fmaf(xv.y, w1.w, acc[r].w);
                acc[r].x = fmaf(xv.z, w2.x, acc[r].x);
                acc[r].y = fmaf(xv.z, w2.y, acc[r].y);
                acc[r].z = fmaf(xv.z, w2.z, acc[r].z);
                acc[r].w = fmaf(xv.z, w2.w, acc[r].w);
                acc[r].x = fmaf(xv.w, w3.x, acc[r].x);
                acc[r].y = fmaf(xv.w, w3.y, acc[r].y);
                acc[r].z = fmaf(xv.w, w3.z, acc[r].z);
                acc[r].w = fmaf(xv.w, w3.w, acc[r].w);
            }
        }
        __syncthreads();
    }
    epi(acc, rp, cg);
}

// ------ combined: proj1 (bf16, un-normalized) || histogram + edge rank (4:1) --
template<int DIN, int DOUT, int RB, int KT>
__global__ void __launch_bounds__(256) k_comb(
        const float* __restrict__ x, const float* __restrict__ W,
        ushort_t* __restrict__ outbf, int N,
        const int* __restrict__ src, const int* __restrict__ dst,
        int* __restrict__ degO, int* __restrict__ degI,
        int* __restrict__ rank, int E, int PB, int HTH) {
    constexpr int CG  = DOUT / 4;
    constexpr int RPP = 256 / CG;
    constexpr int R4  = RB / RPP;
    constexpr int K4T = KT / 4;
    __shared__ float4 wlds[KT * CG];
    __shared__ float4 xlds[RB * K4T];

    int bid = blockIdx.x, g = bid / 5, r = bid - g * 5;
    if (r == 4) {
        // histogram role (1 of every 5 blocks): degrees + per-edge dst rank
        int i = g * 256 + (int)threadIdx.x;
        for (; i < E; i += HTH) {
            atomicAdd(&degO[src[i]], 1);
            rank[i] = atomicAdd(&degI[dst[i]], 1);
        }
        return;
    }
    int pidx = g * 4 + r;
    if (pidx >= PB) return;
    int n0 = pidx * RB;
    proj_body<DIN, DOUT, RB, KT>(x, W, N, n0, wlds, xlds,
        [&](float4 (&acc)[R4], int rp, int cg) {
#pragma unroll
            for (int rr = 0; rr < R4; ++rr) {
                int n = n0 + rp + rr * RPP;
                if (n < N) {
                    ushort4 s;
                    s.x = f2bf(acc[rr].x); s.y = f2bf(acc[rr].y);
                    s.z = f2bf(acc[rr].z); s.w = f2bf(acc[rr].w);
                    *(ushort4*)(outbf + (size_t)n * DOUT + cg * 4) = s;
                }
            }
        });
}

// ---------------- proj, bf16 out with *nrm[n] applied -------------------------
template<int DIN, int DOUT, int RB, int KT>
__global__ void __launch_bounds__(256) k_proj_gl2b(
        const float* __restrict__ in, const float* __restrict__ nrm,
        const float* __restrict__ W, ushort_t* __restrict__ outbf, int N) {
    constexpr int CG  = DOUT / 4;
    constexpr int RPP = 256 / CG;
    constexpr int R4  = RB / RPP;
    constexpr int K4T = KT / 4;
    __shared__ float4 wlds[KT * CG];
    __shared__ float4 xlds[RB * K4T];
    int n0 = blockIdx.x * RB;
    proj_body<DIN, DOUT, RB, KT>(in, W, N, n0, wlds, xlds,
        [&](float4 (&acc)[R4], int rp, int cg) {
#pragma unroll
            for (int rr = 0; rr < R4; ++rr) {
                int n = n0 + rp + rr * RPP;
                if (n < N) {
                    float nm = nrm[n];
                    ushort4 s;
                    s.x = f2bf(acc[rr].x * nm); s.y = f2bf(acc[rr].y * nm);
                    s.z = f2bf(acc[rr].z * nm); s.w = f2bf(acc[rr].w * nm);
                    *(ushort4*)(outbf + (size_t)n * DOUT + cg * 4) = s;
                }
            }
        });
}

// -------- fused: per-block degI sums (for scan) + nSf/nDf precompute ---------
__global__ void k_blocksum(const int* __restrict__ degI, const int* __restrict__ degO,
                           int* __restrict__ bsum, float* __restrict__ nSf,
                           float* __restrict__ nDf, int N) {
    __shared__ int sh[256];
    int base = blockIdx.x * 1024;
    int s = 0;
    for (int i = threadIdx.x; i < 1024; i += 256) {
        int idx = base + i;
        if (idx < N) {
            int d = degI[idx];
            s += d;
            nDf[idx] = rsqrtf((float)(d > 1 ? d : 1));
            int a = degO[idx];
            nSf[idx] = rsqrtf((float)(a > 1 ? a : 1));
        }
    }
    sh[threadIdx.x] = s; __syncthreads();
    for (int off = 128; off > 0; off >>= 1) {
        if (threadIdx.x < off) sh[threadIdx.x] += sh[threadIdx.x + off];
        __syncthreads();
    }
    if (threadIdx.x == 0) bsum[blockIdx.x] = sh[0];
}

__global__ void k_scan_bsums(const int* __restrict__ bsum, int* __restrict__ boffs, int nb) {
    if (blockIdx.x == 0 && threadIdx.x == 0) {
        int run = 0;
        for (int i = 0; i < nb; ++i) { boffs[i] = run; run += bsum[i]; }
    }
}

__global__ void k_blockscan(const int* __restrict__ deg, const int* __restrict__ boffs,
                            int* __restrict__ rowptr, int N) {
    __shared__ int sh[256];
    int base = blockIdx.x * 1024;
    int i0 = base + threadIdx.x * 4;
    int v[4]; int tot = 0;
#pragma unroll
    for (int r = 0; r < 4; ++r) {
        int idx = i0 + r;
        v[r] = (idx < N) ? deg[idx] : 0;
        tot += v[r];
    }
    sh[threadIdx.x] = tot; __syncthreads();
    for (int off = 1; off < 256; off <<= 1) {
        int t = (threadIdx.x >= off) ? sh[threadIdx.x - off] : 0;
        __syncthreads();
        sh[threadIdx.x] += t;
        __syncthreads();
    }
    int run = sh[threadIdx.x] - tot + boffs[blockIdx.x];
#pragma unroll
    for (int r = 0; r < 4; ++r) {
        int idx = i0 + r;
        if (idx < N) rowptr[idx] = run;
        run += v[r];
    }
}

// ---------- atomic-free CSR fill: col[rowptr[dst]+rank] = src ----------------
__global__ void k_fill3(const int* __restrict__ src, const int* __restrict__ dst,
                        const int* __restrict__ rank, const int* __restrict__ rowptr,
                        int* __restrict__ col, int E) {
    int stride = gridDim.x * blockDim.x;
    for (int i = blockIdx.x * blockDim.x + threadIdx.x; i < E; i += stride) {
        col[rowptr[dst[i]] + rank[i]] = src[i];
    }
}

// -------- L1: bf16 gather (128-wide), per-edge nS, 4-edge unroll -------------
__global__ void __launch_bounds__(256) k_gather_l1(
        const int* __restrict__ rowptr, const int* __restrict__ col,
        const int* __restrict__ degI, const float* __restrict__ nSf,
        const float* __restrict__ nDf, const ushort_t* __restrict__ projbf,
        const float* __restrict__ bias, float* __restrict__ out, int N) {
    constexpr int DOUT = 128;
    constexpr int CGB = DOUT / 8;      // 16
    long t = blockIdx.x * 256L + threadIdx.x;
    if (t >= (long)N * CGB) return;
    int n  = (int)(t / CGB);
    int cb = (int)(t - (long)n * CGB);
    int beg = rowptr[n];
    int dg  = degI[n];
    float acc[8];
#pragma unroll
    for (int k = 0; k < 8; ++k) acc[k] = 0.f;
    int i = 0;
    for (; i + 4 <= dg; i += 4) {
        int s0 = col[beg + i],     s1 = col[beg + i + 1];
        int s2 = col[beg + i + 2], s3 = col[beg + i + 3];
        uint4 v0 = *(const uint4*)(projbf + (size_t)s0 * DOUT + cb * 8);
        uint4 v1 = *(const uint4*)(projbf + (size_t)s1 * DOUT + cb * 8);
        uint4 v2 = *(const uint4*)(projbf + (size_t)s2 * DOUT + cb * 8);
        uint4 v3 = *(const uint4*)(projbf + (size_t)s3 * DOUT + cb * 8);
        float n0 = nSf[s0], n1 = nSf[s1], n2 = nSf[s2], n3 = nSf[s3];
        acc[0] = fmaf(n0, BFLO(v0.x), fmaf(n1, BFLO(v1.x), fmaf(n2, BFLO(v2.x), fmaf(n3, BFLO(v3.x), acc[0]))));
        acc[1] = fmaf(n0, BFHI(v0.x), fmaf(n1, BFHI(v1.x), fmaf(n2, BFHI(v2.x), fmaf(n3, BFHI(v3.x), acc[1]))));
        acc[2] = fmaf(n0, BFLO(v0.y), fmaf(n1, BFLO(v1.y), fmaf(n2, BFLO(v2.y), fmaf(n3, BFLO(v3.y), acc[2]))));
        acc[3] = fmaf(n0, BFHI(v0.y), fmaf(n1, BFHI(v1.y), fmaf(n2, BFHI(v2.y), fmaf(n3, BFHI(v3.y), acc[3]))));
        acc[4] = fmaf(n0, BFLO(v0.z), fmaf(n1, BFLO(v1.z), fmaf(n2, BFLO(v2.z), fmaf(n3, BFLO(v3.z), acc[4]))));
        acc[5] = fmaf(n0, BFHI(v0.z), fmaf(n1, BFHI(v1.z), fmaf(n2, BFHI(v2.z), fmaf(n3, BFHI(v3.z), acc[5]))));
        acc[6] = fmaf(n0, BFLO(v0.w), fmaf(n1, BFLO(v1.w), fmaf(n2, BFLO(v2.w), fmaf(n3, BFLO(v3.w), acc[6]))));
        acc[7] = fmaf(n0, BFHI(v0.w), fmaf(n1, BFHI(v1.w), fmaf(n2, BFHI(v2.w), fmaf(n3, BFHI(v3.w), acc[7]))));
    }
    for (; i < dg; ++i) {
        int s0 = col[beg + i];
        uint4 v0 = *(const uint4*)(projbf + (size_t)s0 * DOUT + cb * 8);
        float ns0 = nSf[s0];
        acc[0] = fmaf(ns0, BFLO(v0.x), acc[0]);
        acc[1] = fmaf(ns0, BFHI(v0.x), acc[1]);
        acc[2] = fmaf(ns0, BFLO(v0.y), acc[2]);
        acc[3] = fmaf(ns0, BFHI(v0.y), acc[3]);
        acc[4] = fmaf(ns0, BFLO(v0.z), acc[4]);
        acc[5] = fmaf(ns0, BFHI(v0.z), acc[5]);
        acc[6] = fmaf(ns0, BFLO(v0.w), acc[6]);
        acc[7] = fmaf(ns0, BFHI(v0.w), acc[7]);
    }
    float nm = nDf[n];
    const float* bp = bias + cb * 8;
    float o[8];
#pragma unroll
    for (int k = 0; k < 8; ++k) o[k] = fmaxf(fmaf(acc[k], nm, bp[k]), 0.f);
    float* dstp = out + (size_t)n * DOUT + cb * 8;
    *(float4*)(dstp)     = make_float4(o[0], o[1], o[2], o[3]);
    *(float4*)(dstp + 4) = make_float4(o[4], o[5], o[6], o[7]);
}

// -------- L2 FUSED: bf16 gather (64) -> h2 = relu(sum*nD+b2) -> P3=(h2*nS)@W3 -
__global__ void __launch_bounds__(256) k_gather_fuse2(
        const int* __restrict__ rowptr, const int* __restrict__ col,
        const int* __restrict__ degI, const float* __restrict__ nSf,
        const float* __restrict__ nDf, const ushort_t* __restrict__ p2bf,
        const float* __restrict__ b2, const float* __restrict__ W3,
        float* __restrict__ P3, int N) {
    constexpr int DOUT = 64;
    __shared__ float w3s[64 * 16];     // 4 KB
    ((float4*)w3s)[threadIdx.x] = ((const float4*)W3)[threadIdx.x];  // 256*16B = 4KB
    __syncthreads();

    long t = blockIdx.x * 256L + threadIdx.x;
    int n = (int)(t >> 3);
    bool valid = n < N;
    if (!valid) n = N - 1;
    int cb = (int)(t & 7);
    int lane = threadIdx.x & 63;
    int gb = lane & ~7;

    int beg = rowptr[n];
    int dg  = degI[n];
    float acc[8];
#pragma unroll
    for (int k = 0; k < 8; ++k) acc[k] = 0.f;
    int i = 0;
    for (; i + 4 <= dg; i += 4) {
        int s0 = col[beg + i],     s1 = col[beg + i + 1];
        int s2 = col[beg + i + 2], s3 = col[beg + i + 3];
        uint4 v0 = *(const uint4*)(p2bf + (size_t)s0 * DOUT + cb * 8);
        uint4 v1 = *(const uint4*)(p2bf + (size_t)s1 * DOUT + cb * 8);
        uint4 v2 = *(const uint4*)(p2bf + (size_t)s2 * DOUT + cb * 8);
        uint4 v3 = *(const uint4*)(p2bf + (size_t)s3 * DOUT + cb * 8);
        acc[0] += BFLO(v0.x) + BFLO(v1.x) + BFLO(v2.x) + BFLO(v3.x);
        acc[1] += BFHI(v0.x) + BFHI(v1.x) + BFHI(v2.x) + BFHI(v3.x);
        acc[2] += BFLO(v0.y) + BFLO(v1.y) + BFLO(v2.y) + BFLO(v3.y);
        acc[3] += BFHI(v0.y) + BFHI(v1.y) + BFHI(v2.y) + BFHI(v3.y);
        acc[4] += BFLO(v0.z) + BFLO(v1.z) + BFLO(v2.z) + BFLO(v3.z);
        acc[5] += BFHI(v0.z) + BFHI(v1.z) + BFHI(v2.z) + BFHI(v3.z);
        acc[6] += BFLO(v0.w) + BFLO(v1.w) + BFLO(v2.w) + BFLO(v3.w);
        acc[7] += BFHI(v0.w) + BFHI(v1.w) + BFHI(v2.w) + BFHI(v3.w);
    }
    for (; i < dg; ++i) {
        int s0 = col[beg + i];
        uint4 v0 = *(const uint4*)(p2bf + (size_t)s0 * DOUT + cb * 8);
        acc[0] += BFLO(v0.x); acc[1] += BFHI(v0.x);
        acc[2] += BFLO(v0.y); acc[3] += BFHI(v0.y);
        acc[4] += BFLO(v0.z); acc[5] += BFHI(v0.z);
        acc[6] += BFLO(v0.w); acc[7] += BFHI(v0.w);
    }
    // epilogue: h2 chunk, scaled by nS
    float nm = nDf[n];
    float ns = nSf[n];
    const float* bp = b2 + cb * 8;
    float o[8];
#pragma unroll
    for (int k = 0; k < 8; ++k)
        o[k] = fmaxf(fmaf(acc[k], nm, bp[k]), 0.f) * ns;
    // tiny GEMM: P3[n, 2cb..2cb+1] = h2s @ W3, row exchanged via shfl
    float y0 = 0.f, y1 = 0.f;
#pragma unroll
    for (int k = 0; k < 64; ++k) {
        float v = __shfl(o[k & 7], gb + (k >> 3), 64);
        y0 = fmaf(v, w3s[k * 16 + 2 * cb], y0);
        y1 = fmaf(v, w3s[k * 16 + 2 * cb + 1], y1);
    }
    if (valid) *(float2*)(P3 + (size_t)n * 16 + 2 * cb) = make_float2(y0, y1);
}

// -------- L3: fp32 gather P3 (16) -> t4 = relu(sum*nD+b3)*nS -----------------
__global__ void __launch_bounds__(256) k_gather_l3(
        const int* __restrict__ rowptr, const int* __restrict__ col,
        const int* __restrict__ degI, const float* __restrict__ nSf,
        const float* __restrict__ nDf, const float* __restrict__ proj,
        const float* __restrict__ bias, float* __restrict__ out, int N) {
    long t = blockIdx.x * 256L + threadIdx.x;
    if (t >= (long)N * 4) return;
    int n  = (int)(t >> 2);
    int cg = (int)(t & 3);
    int beg = rowptr[n];
    int dg  = degI[n];
    float4 a0 = make_float4(0.f, 0.f, 0.f, 0.f);
    float4 a1 = make_float4(0.f, 0.f, 0.f, 0.f);
    float4 a2 = make_float4(0.f, 0.f, 0.f, 0.f);
    float4 a3 = make_float4(0.f, 0.f, 0.f, 0.f);
    int i = 0;
    for (; i + 4 <= dg; i += 4) {
        int s0 = col[beg + i],     s1 = col[beg + i + 1];
        int s2 = col[beg + i + 2], s3 = col[beg + i + 3];
        float4 v0 = *(const float4*)(proj + (size_t)s0 * 16 + cg * 4);
        float4 v1 = *(const float4*)(proj + (size_t)s1 * 16 + cg * 4);
        float4 v2 = *(const float4*)(proj + (size_t)s2 * 16 + cg * 4);
        float4 v3 = *(const float4*)(proj + (size_t)s3 * 16 + cg * 4);
        a0.x += v0.x; a0.y += v0.y; a0.z += v0.z; a0.w += v0.w;
        a1.x += v1.x; a1.y += v1.y; a1.z += v1.z; a1.w += v1.w;
        a2.x += v2.x; a2.y += v2.y; a2.z += v2.z; a2.w += v2.w;
        a3.x += v3.x; a3.y += v3.y; a3.z += v3.z; a3.w += v3.w;
    }
    for (; i < dg; ++i) {
        int s0 = col[beg + i];
        float4 v0 = *(const float4*)(proj + (size_t)s0 * 16 + cg * 4);
        a0.x += v0.x; a0.y += v0.y; a0.z += v0.z; a0.w += v0.w;
    }
    float4 s = make_float4(a0.x + a1.x + a2.x + a3.x, a0.y + a1.y + a2.y + a3.y,
                           a0.z + a1.z + a2.z + a3.z, a0.w + a1.w + a2.w + a3.w);
    float nm = nDf[n];
    float ns = nSf[n];
    float4 b = *(const float4*)(bias + cg * 4);
    float4 o;
    o.x = fmaxf(fmaf(s.x, nm, b.x), 0.f) * ns;
    o.y = fmaxf(fmaf(s.y, nm, b.y), 0.f) * ns;
    o.z = fmaxf(fmaf(s.z, nm, b.z), 0.f) * ns;
    o.w = fmaxf(fmaf(s.w, nm, b.w), 0.f) * ns;
    *(float4*)(out + (size_t)n * 16 + cg * 4) = o;
}

// -------- L4 FUSED: gather t4 (16) -> out = (agg@W4)*nD + b4 (40 wide) -------
__global__ void __launch_bounds__(256) k_gather_fuse4(
        const int* __restrict__ rowptr, const int* __restrict__ col,
        const int* __restrict__ degI, const float* __restrict__ nDf,
        const float* __restrict__ t4, const float* __restrict__ W4,
        const float* __restrict__ b4, float* __restrict__ out, int N) {
    __shared__ float w4s[16 * 40];     // 2.56 KB
    __shared__ float b4s[40];
    for (int i = threadIdx.x; i < 160; i += 256)
        ((float4*)w4s)[i] = ((const float4*)W4)[i];
    if (threadIdx.x < 40) b4s[threadIdx.x] = b4[threadIdx.x];
    __syncthreads();

    long t = blockIdx.x * 256L + threadIdx.x;
    int n = (int)(t >> 2);
    bool valid = n < N;
    if (!valid) n = N - 1;
    int cg = (int)(t & 3);
    int lane = threadIdx.x & 63;
    int gb = lane & ~3;

    int beg = rowptr[n];
    int dg  = degI[n];
    float4 a0 = make_float4(0.f, 0.f, 0.f, 0.f);
    float4 a1 = make_float4(0.f, 0.f, 0.f, 0.f);
    int i = 0;
    for (; i + 2 <= dg; i += 2) {
        int s0 = col[beg + i], s1 = col[beg + i + 1];
        float4 v0 = *(const float4*)(t4 + (size_t)s0 * 16 + cg * 4);
        float4 v1 = *(const float4*)(t4 + (size_t)s1 * 16 + cg * 4);
        a0.x += v0.x; a0.y += v0.y; a0.z += v0.z; a0.w += v0.w;
        a1.x += v1.x; a1.y += v1.y; a1.z += v1.z; a1.w += v1.w;
    }
    if (i < dg) {
        int s0 = col[beg + i];
        float4 v0 = *(const float4*)(t4 + (size_t)s0 * 16 + cg * 4);
        a0.x += v0.x; a0.y += v0.y; a0.z += v0.z; a0.w += v0.w;
    }
    float av[4] = { a0.x + a1.x, a0.y + a1.y, a0.z + a1.z, a0.w + a1.w };

    float y[10];
#pragma unroll
    for (int jj = 0; jj < 10; ++jj) y[jj] = 0.f;
#pragma unroll
    for (int k = 0; k < 16; ++k) {
        float v = __shfl(av[k & 3], gb + (k >> 2), 64);
        const float* wr = w4s + k * 40 + cg * 10;
#pragma unroll
        for (int jj = 0; jj < 10; ++jj) y[jj] = fmaf(v, wr[jj], y[jj]);
    }
    if (valid) {
        float nm = nDf[n];
        float* dp = out + (size_t)n * 40 + cg * 10;
        const float* bp = b4s + cg * 10;
#pragma unroll
        for (int jj = 0; jj < 10; ++jj) dp[jj] = fmaf(y[jj], nm, bp[jj]);
    }
}

static inline int cdiv(long a, int b) { return (int)((a + b - 1) / b); }

extern "C" void kernel_launch(void* const* d_in, const int* in_sizes, int n_in,
                              void* d_out, int out_size, void* d_ws, size_t ws_size,
                              hipStream_t stream) {
    const float* x   = (const float*)d_in[0];
    const int*   src = (const int*)d_in[1];
    const int*   dst = (const int*)d_in[2];
    const float* W1 = (const float*)d_in[3];  const float* b1 = (const float*)d_in[4];
    const float* W2 = (const float*)d_in[5];  const float* b2 = (const float*)d_in[6];
    const float* W3 = (const float*)d_in[7];  const float* b3 = (const float*)d_in[8];
    const float* W4 = (const float*)d_in[9];  const float* b4 = (const float*)d_in[10];

    const int N = in_sizes[0] / 256;
    const int E = in_sizes[1];

    // ---- workspace layout ----
    int* ws_i = (int*)d_ws;
    int* degO   = ws_i;                       // [N]
    int* degI   = ws_i + N;                   // [N]
    int* rowptr = ws_i + 2 * (size_t)N;       // [N]
    int* col    = ws_i + 3 * (size_t)N;       // [E]
    int* rank   = ws_i + 3 * (size_t)N + E;   // [E]
    float* nSf  = (float*)(ws_i + 3 * (size_t)N + 2 * (size_t)E);  // [N]
    float* nDf  = nSf + N;                    // [N]
    float* projb = nDf + N;                   // N*64 f32 region: P1 bf16 (N*64f) / P2 bf16 (N*32f) + P3 f32 (N*16f)
    float* hbuf  = projb + (size_t)N * 64;    // N*128 f32 (h1 / t4)
    ushort_t* projbf = (ushort_t*)projb;
    float* P3 = projb + (size_t)N * 32;       // after P2's bf16 region
    // CSR-build scratch aliased into hbuf (dead before first hbuf write)
    int* bsum   = (int*)hbuf;                 // [<=4096]
    int* boffs  = bsum + 4096;                // [<=4096]

    int nb = (N + 1023) / 1024;
    int PB = cdiv(N, 64);
    int G5 = cdiv(PB, 4);
    int HTH = G5 * 256;

    // ---- combined: histogram+rank || proj1 (bf16, un-normalized), 4:1 ----
    hipMemsetAsync(degO, 0, 2 * (size_t)N * sizeof(int), stream);
    k_comb<256, 128, 64, 32><<<5 * G5, 256, 0, stream>>>(
        x, W1, projbf, N, src, dst, degO, degI, rank, E, PB, HTH);

    // ---- norms + CSR (fused blocksum+prep; atomic-free fill) ----
    k_blocksum<<<nb, 256, 0, stream>>>(degI, degO, bsum, nSf, nDf, N);
    k_scan_bsums<<<1, 64, 0, stream>>>(bsum, boffs, nb);
    k_blockscan<<<nb, 256, 0, stream>>>(degI, boffs, rowptr, N);
    k_fill3<<<2048, 256, 0, stream>>>(src, dst, rank, rowptr, col, E);

    // ---- layer 1 aggregate: bf16 gather w/ per-edge nS -> hbuf (h1) ----
    k_gather_l1<<<cdiv((long)N * 16, 256), 256, 0, stream>>>(
        rowptr, col, degI, nSf, nDf, projbf, b1, hbuf, N);

    // ---- layer 2: proj (h1@W2)*nS -> P2 bf16; FUSED gather+P3 GEMM ----
    k_proj_gl2b<128, 64, 64, 32><<<cdiv(N, 64), 256, 0, stream>>>(
        hbuf, nSf, W2, projbf, N);
    k_gather_fuse2<<<cdiv((long)N * 8, 256), 256, 0, stream>>>(
        rowptr, col, degI, nSf, nDf, projbf, b2, W3, P3, N);

    // ---- layer 3: gather P3 -> t4 (relu+nD+b3, *nS) -> hbuf ----
    k_gather_l3<<<cdiv((long)N * 4, 256), 256, 0, stream>>>(
        rowptr, col, degI, nSf, nDf, P3, b3, hbuf, N);

    // ---- layer 4 FUSED: gather t4 + (agg@W4)*nD+b4 -> out ----
    k_gather_fuse4<<<cdiv((long)N * 4, 256), 256, 0, stream>>>(
        rowptr, col, degI, nDf, hbuf, W4, b4, (float*)d_out, N);
}